// Round 2
// baseline (209.032 us; speedup 1.0000x reference)
//
#include <hip/hip_runtime.h>

#define CH 32  // steps per chunk (N = 4194304 is divisible by 32)

// Reference step: s <- sigmoid(10*((s + u) - 0.5)); mirror the op order.
// Every op is monotone non-decreasing in s (add, mul by +10, exp monotone,
// 1/(1+e) monotone in -e, IEEE divide is correctly rounded hence monotone),
// so the chunk map is monotone in the incoming state: bracketing with s=0
// and s=1 is exact — if both brackets land on identical floats, ANY incoming
// state in [0,1] lands there too.
__device__ __forceinline__ float sig10(float s, float u) {
    float t = (s + u) - 0.5f;
    float a = 10.0f * t;
    float e = __expf(-a);
    return 1.0f / (1.0f + e);   // IEEE divide (no fast-math): monotone
}

__device__ __forceinline__ void step3(float& s0, float& s1, float& s2,
                                      float u0, float u1, float u2) {
    s0 = sig10(s0, u0);
    s1 = sig10(s1, u1);
    s2 = sig10(s2, u2);
}

// Phase 1: per chunk, run the recurrence from both bracket states (0 and 1).
// If they collapse to identical floats, the chunk's outgoing state is
// independent of its incoming state. Write the candidate incoming state for
// the NEXT chunk plus a "not collapsed" flag.
__global__ void __launch_bounds__(256) p1_bracket(
    const float* __restrict__ update, float* __restrict__ state_in,
    int* __restrict__ flags, int C, int N) {
    int c = blockIdx.x * blockDim.x + threadIdx.x;
    if (c >= C) return;
    float a0 = 0.f, a1 = 0.f, a2 = 0.f;   // from s = 0
    float b0 = 1.f, b1 = 1.f, b2 = 1.f;   // from s = 1
    if ((size_t)(c + 1) * CH <= (size_t)N) {
        // full chunk, float4 fast path (chunk base 384B-aligned)
        const float4* up4 = (const float4*)(update + (size_t)c * CH * 3);
#pragma unroll
        for (int g = 0; g < CH / 4; ++g) {
            float4 A = up4[3 * g + 0];
            float4 B = up4[3 * g + 1];
            float4 Cv = up4[3 * g + 2];
            step3(a0, a1, a2, A.x, A.y, A.z);  step3(b0, b1, b2, A.x, A.y, A.z);
            step3(a0, a1, a2, A.w, B.x, B.y);  step3(b0, b1, b2, A.w, B.x, B.y);
            step3(a0, a1, a2, B.z, B.w, Cv.x); step3(b0, b1, b2, B.z, B.w, Cv.x);
            step3(a0, a1, a2, Cv.y, Cv.z, Cv.w); step3(b0, b1, b2, Cv.y, Cv.z, Cv.w);
        }
    } else {
        const float* up = update + (size_t)c * CH * 3;
        int steps = N - c * CH;
        for (int i = 0; i < steps; ++i) {
            step3(a0, a1, a2, up[3 * i], up[3 * i + 1], up[3 * i + 2]);
            step3(b0, b1, b2, up[3 * i], up[3 * i + 1], up[3 * i + 2]);
        }
    }
    flags[c] = !(a0 == b0 && a1 == b1 && a2 == b2);
    if (c + 1 < C) {
        state_in[(size_t)(c + 1) * 3 + 0] = a0;
        state_in[(size_t)(c + 1) * 3 + 1] = a1;
        state_in[(size_t)(c + 1) * 3 + 2] = a2;
    }
}

// Phase 2: (a) parallel check whether ANY chunk failed to collapse;
// (b) thread 0 resolves chunk 0 exactly from network0 (which may lie outside
//     the [0,1] bracket), and — only if needed — sequentially repairs the
//     (essentially nonexistent) non-collapsed chunks in ascending order.
__global__ void p2_fix(const float* __restrict__ update,
                       const float* __restrict__ net0,
                       float* __restrict__ state_in,
                       const int* __restrict__ flags, int C, int N) {
    __shared__ int s_any;
    if (threadIdx.x == 0) s_any = 0;
    __syncthreads();
    int bad = 0;
    for (int c = threadIdx.x; c < C; c += blockDim.x) bad |= flags[c];
    if (bad) atomicOr(&s_any, 1);
    __syncthreads();
    if (threadIdx.x != 0) return;
    int any = s_any;

    float s0 = net0[0], s1 = net0[1], s2 = net0[2];
    state_in[0] = s0; state_in[1] = s1; state_in[2] = s2;
    {   // chunk 0: always resolved exactly (net0 may be outside [0,1])
        const float* up = update;
        int steps = min(CH, N);
        for (int i = 0; i < steps; ++i)
            step3(s0, s1, s2, up[3 * i], up[3 * i + 1], up[3 * i + 2]);
        if (C > 1) { state_in[3] = s0; state_in[4] = s1; state_in[5] = s2; }
    }
    if (!any) return;
    for (int c = 1; c < C; ++c) {  // exact repair path (~0.1 expected chunks)
        if (!flags[c]) continue;
        float t0 = state_in[(size_t)c * 3 + 0];
        float t1 = state_in[(size_t)c * 3 + 1];
        float t2 = state_in[(size_t)c * 3 + 2];
        const float* up = update + (size_t)c * CH * 3;
        int steps = min(CH, N - c * CH);
        for (int i = 0; i < steps; ++i)
            step3(t0, t1, t2, up[3 * i], up[3 * i + 1], up[3 * i + 2]);
        if (c + 1 < C) {
            state_in[(size_t)(c + 1) * 3 + 0] = t0;
            state_in[(size_t)(c + 1) * 3 + 1] = t1;
            state_in[(size_t)(c + 1) * 3 + 2] = t2;
        }
    }
}

// Phase 3: each chunk replays its steps from the exact incoming state and
// writes the predictions (same map as p1 => bitwise-consistent states).
__global__ void __launch_bounds__(256) p3_emit(
    const float* __restrict__ x, const float* __restrict__ update,
    const float* __restrict__ state_in, float* __restrict__ out, int C, int N) {
    int c = blockIdx.x * blockDim.x + threadIdx.x;
    if (c >= C) return;
    float s0 = state_in[(size_t)c * 3 + 0];
    float s1 = state_in[(size_t)c * 3 + 1];
    float s2 = state_in[(size_t)c * 3 + 2];
    if ((size_t)(c + 1) * CH <= (size_t)N) {
        const float4* up4 = (const float4*)(update + (size_t)c * CH * 3);
        const float4* xp4 = (const float4*)(x + (size_t)c * CH * 3);
        float4* op4 = (float4*)(out + (size_t)c * CH);
#pragma unroll
        for (int g = 0; g < CH / 4; ++g) {
            float4 UA = up4[3 * g + 0], UB = up4[3 * g + 1], UC = up4[3 * g + 2];
            float4 XA = xp4[3 * g + 0], XB = xp4[3 * g + 1], XC = xp4[3 * g + 2];
            float4 o;
            step3(s0, s1, s2, UA.x, UA.y, UA.z);
            o.x = XA.x * s0 + XA.y * s1 + XA.z * s2;
            step3(s0, s1, s2, UA.w, UB.x, UB.y);
            o.y = XA.w * s0 + XB.x * s1 + XB.y * s2;
            step3(s0, s1, s2, UB.z, UB.w, UC.x);
            o.z = XB.z * s0 + XB.w * s1 + XC.x * s2;
            step3(s0, s1, s2, UC.y, UC.z, UC.w);
            o.w = XC.y * s0 + XC.z * s1 + XC.w * s2;
            op4[g] = o;
        }
    } else {
        const float* up = update + (size_t)c * CH * 3;
        const float* xp = x + (size_t)c * CH * 3;
        float* op = out + (size_t)c * CH;
        int steps = N - c * CH;
        for (int i = 0; i < steps; ++i) {
            step3(s0, s1, s2, up[3 * i], up[3 * i + 1], up[3 * i + 2]);
            op[i] = xp[3 * i] * s0 + xp[3 * i + 1] * s1 + xp[3 * i + 2] * s2;
        }
    }
}

extern "C" void kernel_launch(void* const* d_in, const int* in_sizes, int n_in,
                              void* d_out, int out_size, void* d_ws, size_t ws_size,
                              hipStream_t stream) {
    const float* x      = (const float*)d_in[0];   // [N,1,3]
    const float* update = (const float*)d_in[1];   // [N,3,1]
    const float* net0   = (const float*)d_in[2];   // [3,1]
    float* out = (float*)d_out;                    // [N,1]
    int N = out_size;
    int C = (N + CH - 1) / CH;

    // workspace: state_in (C*3 floats) | flags (C ints) — ~2.1 MB total
    float* state_in = (float*)d_ws;
    int*   flags    = (int*)((char*)d_ws + (size_t)C * 3 * sizeof(float));

    int threads = 256;
    int blocks = (C + threads - 1) / threads;
    hipLaunchKernelGGL(p1_bracket, dim3(blocks), dim3(threads), 0, stream,
                       update, state_in, flags, C, N);
    hipLaunchKernelGGL(p2_fix, dim3(1), dim3(1024), 0, stream,
                       update, net0, state_in, flags, C, N);
    hipLaunchKernelGGL(p3_emit, dim3(blocks), dim3(threads), 0, stream,
                       x, update, state_in, out, C, N);
}

// Round 7
// 151.338 us; speedup vs baseline: 1.3812x; 1.3812x over previous
//
#include <hip/hip_runtime.h>

#define CH 32    // steps per chunk (N = 4194304 divisible by 32)
#define TPB 256

// Reference step: s <- sigmoid(10*((s + u) - 0.5)) — identical ops/order to the
// PASSED R2 kernel (absmax 0.0078 vs 0.1575 threshold). Every op is monotone
// non-decreasing in s for all real s, so the chunk map is monotone: if the
// trajectories from lo and 1 land on identical floats, any start in [lo,1]
// lands there too. lo=0 for chunks>=1 (incoming state is a sigmoid output);
// lo=-1 for chunk 0 (net0 in (-1,1]) — and chunk 0 is ALSO recomputed exactly
// from net0 in p2, so its flag only matters for the (harmless) any-check.
__device__ __forceinline__ float sig10(float s, float u) {
    float t = (s + u) - 0.5f;
    float a = 10.0f * t;
    float e = __expf(-a);
    return 1.0f / (1.0f + e);   // IEEE divide: monotone
}

__device__ __forceinline__ void step3(float& s0, float& s1, float& s2,
                                      float u0, float u1, float u2) {
    s0 = sig10(s0, u0); s1 = sig10(s1, u1); s2 = sig10(s2, u2);
}

// ---- Phase 1: bracket each chunk; emit candidate incoming state for chunk c+1
// and a per-chunk "not collapsed" flag + per-block OR of flags.
__global__ void __launch_bounds__(TPB, 2) p1_bracket(
    const float* __restrict__ update, float* __restrict__ state_in,
    int* __restrict__ flags, int* __restrict__ blockflags, int C, int N) {
  __shared__ int s_w[TPB / 64];
  const int tid = threadIdx.x;
  if (tid < TPB / 64) s_w[tid] = 0;
  __syncthreads();
  const int c = blockIdx.x * TPB + tid;
  const bool have = (c < C);
  const bool full = have && ((size_t)(c + 1) * CH <= (size_t)N);
  int flag = 0;
  float a0 = 0.f, a1 = 0.f, a2 = 0.f;
  if (full) {
    const float4* up4 = (const float4*)(update + (size_t)c * (CH * 3));
    float4 u[24];
#pragma unroll
    for (int g = 0; g < 24; ++g) u[g] = up4[g];   // batch-issue all 24 loads
    const float lo = (c == 0) ? -1.0f : 0.0f;
    a0 = a1 = a2 = lo;
    float b0 = 1.f, b1 = 1.f, b2 = 1.f;
    bool bdone = false;
#pragma unroll
    for (int g = 0; g < 8; ++g) {
      const float4 A = u[3 * g], B = u[3 * g + 1], Cv = u[3 * g + 2];
      step3(a0, a1, a2, A.x, A.y, A.z);
      step3(a0, a1, a2, A.w, B.x, B.y);
      step3(a0, a1, a2, B.z, B.w, Cv.x);
      step3(a0, a1, a2, Cv.y, Cv.z, Cv.w);
      if (!bdone) {                 // wave-uniform early exit of upper bracket
        step3(b0, b1, b2, A.x, A.y, A.z);
        step3(b0, b1, b2, A.w, B.x, B.y);
        step3(b0, b1, b2, B.z, B.w, Cv.x);
        step3(b0, b1, b2, Cv.y, Cv.z, Cv.w);
        bdone = __all((a0 == b0) && (a1 == b1) && (a2 == b2));
      }
    }
    flag = bdone ? 0 : 1;  // conservative (per-wave); exact repair path covers it
  } else if (have) {
    // tail chunk (not hit for N=4194304)
    const float* up = update + (size_t)c * (CH * 3);
    int steps = N - c * CH;
    const float lo = (c == 0) ? -1.0f : 0.0f;
    a0 = a1 = a2 = lo;
    float b0 = 1.f, b1 = 1.f, b2 = 1.f;
    for (int i = 0; i < steps; ++i) {
      step3(a0, a1, a2, up[3 * i], up[3 * i + 1], up[3 * i + 2]);
      step3(b0, b1, b2, up[3 * i], up[3 * i + 1], up[3 * i + 2]);
    }
    flag = !((a0 == b0) && (a1 == b1) && (a2 == b2));
  }
  if (have) {
    if (c + 1 < C) {
      state_in[(size_t)(c + 1) * 3 + 0] = a0;
      state_in[(size_t)(c + 1) * 3 + 1] = a1;
      state_in[(size_t)(c + 1) * 3 + 2] = a2;
    }
    flags[c] = flag;
  }
  unsigned long long bal = __ballot(flag != 0);
  if ((tid & 63) == 0) s_w[tid >> 6] = (bal != 0ull) ? 1 : 0;
  __syncthreads();
  if (tid == 0) {
    int bf = 0;
#pragma unroll
    for (int w = 0; w < TPB / 64; ++w) bf |= s_w[w];
    blockflags[blockIdx.x] = bf;
  }
}

// ---- Phase 2: resolve chunk 0 exactly from net0; if any block flagged,
// sequentially repair flagged chunks in ascending order (exact; ~never taken).
__global__ void p2_fix(const float* __restrict__ update,
                       const float* __restrict__ net0,
                       float* __restrict__ state_in,
                       const int* __restrict__ flags,
                       const int* __restrict__ blockflags,
                       int C, int N, int NBLK) {
  __shared__ int s_any;
  if (threadIdx.x == 0) s_any = 0;
  __syncthreads();
  int bad = 0;
  for (int i = threadIdx.x; i < NBLK; i += blockDim.x) bad |= blockflags[i];
  if (bad) atomicOr(&s_any, 1);
  __syncthreads();
  if (threadIdx.x != 0) return;
  const int any = s_any;

  float s0 = net0[0], s1 = net0[1], s2 = net0[2];
  state_in[0] = s0; state_in[1] = s1; state_in[2] = s2;
  {  // chunk 0: always exact
    const float* up = update;
    int steps = min(CH, N);
    for (int i = 0; i < steps; ++i)
      step3(s0, s1, s2, up[3 * i], up[3 * i + 1], up[3 * i + 2]);
    if (C > 1) { state_in[3] = s0; state_in[4] = s1; state_in[5] = s2; }
  }
  if (!any) return;
  for (int blk = 0; blk < NBLK; ++blk) {
    if (!blockflags[blk]) continue;
    int cc0 = blk * TPB; if (cc0 == 0) cc0 = 1;   // chunk 0 already exact
    int cc1 = min(blk * TPB + TPB, C);
    for (int cc = cc0; cc < cc1; ++cc) {
      if (!flags[cc]) continue;
      float t0 = state_in[(size_t)cc * 3 + 0];
      float t1 = state_in[(size_t)cc * 3 + 1];
      float t2 = state_in[(size_t)cc * 3 + 2];
      const float* up = update + (size_t)cc * (CH * 3);
      int steps = min(CH, N - cc * CH);
      for (int i = 0; i < steps; ++i)
        step3(t0, t1, t2, up[3 * i], up[3 * i + 1], up[3 * i + 2]);
      if (cc + 1 < C) {
        state_in[(size_t)(cc + 1) * 3 + 0] = t0;
        state_in[(size_t)(cc + 1) * 3 + 1] = t1;
        state_in[(size_t)(cc + 1) * 3 + 2] = t2;
      }
    }
  }
}

// ---- Phase 3: replay each chunk from its exact incoming state; stage outputs
// in LDS (stride-33 dwords: 2-way banks = free) and store fully coalesced.
__global__ void __launch_bounds__(TPB, 2) p3_emit(
    const float* __restrict__ x, const float* __restrict__ update,
    const float* __restrict__ state_in, float* __restrict__ out, int C, int N) {
  __shared__ float s_out[TPB * 33];   // 33.8 KB
  const int tid = threadIdx.x;
  const int c = blockIdx.x * TPB + tid;
  const bool fullBlock = ((size_t)(blockIdx.x + 1) * (TPB * CH) <= (size_t)N);
  if (fullBlock) {
    const float4* up4 = (const float4*)(update + (size_t)c * (CH * 3));
    const float4* xp4 = (const float4*)(x + (size_t)c * (CH * 3));
    float s0 = state_in[(size_t)c * 3 + 0];
    float s1 = state_in[(size_t)c * 3 + 1];
    float s2 = state_in[(size_t)c * 3 + 2];
    float4 u[24], xv[24];
#pragma unroll
    for (int g = 0; g < 24; ++g) u[g] = up4[g];     // batch: 48 loads in flight
#pragma unroll
    for (int g = 0; g < 24; ++g) xv[g] = xp4[g];
#pragma unroll
    for (int g = 0; g < 8; ++g) {
      const float4 UA = u[3 * g], UB = u[3 * g + 1], UC = u[3 * g + 2];
      const float4 XA = xv[3 * g], XB = xv[3 * g + 1], XC = xv[3 * g + 2];
      float o0, o1, o2, o3;
      step3(s0, s1, s2, UA.x, UA.y, UA.z); o0 = XA.x * s0 + XA.y * s1 + XA.z * s2;
      step3(s0, s1, s2, UA.w, UB.x, UB.y); o1 = XA.w * s0 + XB.x * s1 + XB.y * s2;
      step3(s0, s1, s2, UB.z, UB.w, UC.x); o2 = XB.z * s0 + XB.w * s1 + XC.x * s2;
      step3(s0, s1, s2, UC.y, UC.z, UC.w); o3 = XC.y * s0 + XC.z * s1 + XC.w * s2;
      s_out[tid * 33 + g * 4 + 0] = o0;   // banks (tid + j) % 32: 2-way, free
      s_out[tid * 33 + g * 4 + 1] = o1;
      s_out[tid * 33 + g * 4 + 2] = o2;
      s_out[tid * 33 + g * 4 + 3] = o3;
    }
    __syncthreads();
    float* ob = out + (size_t)blockIdx.x * (TPB * CH);
#pragma unroll
    for (int k = 0; k < 32; ++k) {
      int f = k * TPB + tid;          // dword index in block's 8192-float slab
      int t = f >> 5, idx = f & 31;   // owning chunk, offset
      ob[f] = s_out[t * 33 + idx];    // wave writes 256B contiguous per inst
    }
  } else if (c < C) {
    // tail (not hit for N=4194304)
    float s0 = state_in[(size_t)c * 3 + 0];
    float s1 = state_in[(size_t)c * 3 + 1];
    float s2 = state_in[(size_t)c * 3 + 2];
    const float* up = update + (size_t)c * (CH * 3);
    const float* xp = x + (size_t)c * (CH * 3);
    float* op = out + (size_t)c * CH;
    int steps = min(CH, N - c * CH);
    for (int i = 0; i < steps; ++i) {
      step3(s0, s1, s2, up[3 * i], up[3 * i + 1], up[3 * i + 2]);
      op[i] = xp[3 * i] * s0 + xp[3 * i + 1] * s1 + xp[3 * i + 2] * s2;
    }
  }
}

extern "C" void kernel_launch(void* const* d_in, const int* in_sizes, int n_in,
                              void* d_out, int out_size, void* d_ws, size_t ws_size,
                              hipStream_t stream) {
    const float* x      = (const float*)d_in[0];   // [N,1,3]
    const float* update = (const float*)d_in[1];   // [N,3,1]
    const float* net0   = (const float*)d_in[2];   // [3,1]
    float* out = (float*)d_out;                    // [N,1]
    int N = out_size;
    int C = (N + CH - 1) / CH;
    int nblk = (C + TPB - 1) / TPB;

    // workspace: state_in (C*3 f32) | flags (C int) | blockflags (nblk int)
    float* state_in = (float*)d_ws;
    int* flags = (int*)((char*)d_ws + (size_t)C * 3 * sizeof(float));
    int* blockflags = flags + C;

    hipLaunchKernelGGL(p1_bracket, dim3(nblk), dim3(TPB), 0, stream,
                       update, state_in, flags, blockflags, C, N);
    hipLaunchKernelGGL(p2_fix, dim3(1), dim3(1024), 0, stream,
                       update, net0, state_in, flags, blockflags, C, N, nblk);
    hipLaunchKernelGGL(p3_emit, dim3(nblk), dim3(TPB), 0, stream,
                       x, update, state_in, out, C, N);
}